// Round 5
// baseline (487.225 us; speedup 1.0000x reference)
//
#include <hip/hip_runtime.h>
#include <stdint.h>

#define HW 16384
#define CDIM 768
#define EPSF 1e-8f

typedef float f32x4  __attribute__((ext_vector_type(4)));
typedef float f32x16 __attribute__((ext_vector_type(16)));
typedef int   i32x8  __attribute__((ext_vector_type(8)));
typedef uint32_t u32x4 __attribute__((ext_vector_type(4)));

__device__ inline void async16(const void* g, void* l) {
    __builtin_amdgcn_global_load_lds(
        (const __attribute__((address_space(1))) uint32_t*)g,
        (__attribute__((address_space(3))) uint32_t*)l, 16, 0, 0);
}

__device__ inline uint32_t pk4_fp8(float v0, float v1, float v2, float v3) {
    uint32_t r = __builtin_amdgcn_cvt_pk_fp8_f32(v0, v1, 0, false);
    r = __builtin_amdgcn_cvt_pk_fp8_f32(v2, v3, r, true);
    return r;   // bytes [v0,v1,v2,v3] little-endian
}

// ---- Kernel 1: fused transpose [C][HW] fp32 -> [HW][C] fp8 + column sum-sq ----
// z=0: a (scale x16), z=1: b (scale x8, RAW; normalization in GEMM epilogue).
__global__ void __launch_bounds__(256)
transpose_fp8_norm(const float* __restrict__ a, const float* __restrict__ b,
                   uint8_t* __restrict__ at8, uint8_t* __restrict__ bn8,
                   float* __restrict__ sumsq_a, float* __restrict__ sumsq_b) {
    const int z = blockIdx.z;
    const float* src = z ? b : a;
    uint8_t* dst = z ? bn8 : at8;
    float* sums = z ? sumsq_b : sumsq_a;
    const float mult = z ? 8.0f : 16.0f;

    __shared__ float tile[64][65];   // [channel][spatial], +1 pad
    const int s0 = blockIdx.x * 64, c0 = blockIdx.y * 64;
    const int tx = threadIdx.x & 63, ty = threadIdx.x >> 6;
#pragma unroll
    for (int p = 0; p < 16; ++p) {
        int cl = p * 4 + ty;
        tile[cl][tx] = src[(size_t)(c0 + cl) * HW + s0 + tx];
    }
    __syncthreads();

    const int chgrp = tx & 15, rowsub = tx >> 4;
    uint32_t* dst32 = (uint32_t*)dst;
#pragma unroll
    for (int p = 0; p < 4; ++p) {
        int sl = p * 16 + ty * 4 + rowsub;
        float v0 = tile[chgrp * 4 + 0][sl];
        float v1 = tile[chgrp * 4 + 1][sl];
        float v2 = tile[chgrp * 4 + 2][sl];
        float v3 = tile[chgrp * 4 + 3][sl];
        float part = v0 * v0 + v1 * v1 + v2 * v2 + v3 * v3;  // raw sum-sq
        dst32[(size_t)(s0 + sl) * (CDIM / 4) + (c0 >> 2) + chgrp] =
            pk4_fp8(v0 * mult, v1 * mult, v2 * mult, v3 * mult);
#pragma unroll
        for (int m = 1; m < 16; m <<= 1) part += __shfl_xor(part, m, 64);
        if (chgrp == 0) atomicAdd(&sums[s0 + sl], part);
    }
}

// ---- Kernel 1b: precompute inverse denominators for b (after atomics) ----
__global__ void prep_invd(const float* __restrict__ sumsq_b,
                          float* __restrict__ invdb) {
    int j = blockIdx.x * 256 + threadIdx.x;
    invdb[j] = 1.0f / (sqrtf(sumsq_b[j] + EPSF) + EPSF);
}

// ---- Kernel 2: MX-scaled fp8 GEMM + normalize + argmax epilogue ----
// Round 13: keep round-4 geometry (256x128 block, wave tile 128x64,
// read:MFMA ratio 1.5 -- its ~150us/CU LDS floor beats round-3's 205us),
// fix its LATENCY problem. Round 4 measured: MfmaUtil 26% x 339us = 88us
// = exact MFMA floor; all pipes <30%; 232 unified regs -> 2 blocks/CU ->
// no TLP to cover the per-tile vmcnt(0) drain (~500cy exposed per tile).
// Fix (T4): 3-buffer pipeline, counted vmcnt -- NEVER drain to 0 in the
// loop. Iter t: vmcnt(6) [newest tile's 6 loads stay in flight => tile t
// landed] -> barrier -> STAGE(t+2 -> buf (t+2)%3) -> COMPUTE(t, buf t%3).
// Loads get TWO compute phases (~1000cy) to land; ILP replaces TLP.
// WAR safe: buffer staged at iter t was computed at iter t-1; each wave's
// reads are lgkm-drained by its MFMAs before it reaches the barrier that
// precedes the overwriting stage. Last two tiles peeled (vmcnt(6), then
// vmcnt(0) once). Hand-unrolled x3 so buffer offsets are literals.
// T5: setprio(1) around MFMA cluster (2 pipelined blocks/CU = role
// diversity). LDS 3 x 24KB = 72KB, still 2 blocks/CU.
// Same swizzle involution (64B rows, XOR key (row>>1)&3); swapped
// operands -> lane-local argmax. C/D 32x32: col=lane&31,
// row=(reg&3)+8*(reg>>2)+4*(lane>>5).
__global__ void __launch_bounds__(256, 2)
gemm_argmax(const uint8_t* __restrict__ at8, const uint8_t* __restrict__ bn8,
            const float* __restrict__ invdb,
            unsigned long long* __restrict__ best) {
    __shared__ uint8_t Al[3 * 16384];   // [buf][256 rows][64 B]
    __shared__ uint8_t Bl[3 * 8192];    // [buf][128 rows][64 B]

    const int g = blockIdx.x;          // 0..8191
    const int xcd    = g & 7;
    const int s      = g >> 3;         // 0..1023
    const int super  = s >> 5;         // 0..31
    const int within = s & 31;         // 32 blocks / supertile (4i x 8j)
    const int si = super >> 4;         // 0..1
    const int sj = super & 15;         // 0..15
    const int it = xcd * 8 + si * 4 + (within & 3);   // 0..63
    const int jt = sj * 8 + (within >> 2);            // 0..127

    const int i0 = it * 256, j0 = jt * 128;
    const int tid = threadIdx.x;
    const int lane = tid & 63, w = tid >> 6;
    const int wi = w & 1, wj = w >> 1;
    const int l31 = lane & 31, hi = lane >> 5;

    f32x16 acc[2][4] = {};   // [nj][mi]: rows j (regs), cols i (lanes)

    // staging (per 1KB issue: 16 rows x 64B): lane l -> row (l>>2),
    // global chunk (l&3)^((l>>3)&3) [== (row>>1)&3], LDS linear.
    const int srow = lane >> 2;
    const int schunk = ((lane & 3) ^ ((lane >> 3) & 3)) * 16;
    // wave stages 64 rows of A (4 issues), 32 rows of B (2 issues)
    const uint8_t* gA = at8 + (size_t)(i0 + w * 64 + srow) * CDIM + schunk;
    const uint8_t* gB = bn8 + (size_t)(j0 + w * 32 + srow) * CDIM + schunk;
    uint8_t* lA = Al + w * 4096;
    uint8_t* lB = Bl + w * 2048;

    // fragment reads: A row = wi*128 + mi*32 + l31; B row = wj*64 + nj*32 + l31
    // lane K-bytes hi*32.. -> logical chunks hi*2, hi*2+1; phys = ^((row>>1)&3)
    const int rA0 = (wi * 128 + l31) * 64;
    const int rB0 = (wj * 64 + l31) * 64;
    const int c0 = ((hi * 2) ^ ((l31 >> 1) & 3)) * 16;   // pair at c0^16

#define STAGE(boA, boB, kk)                                    \
    do {                                                       \
        async16(gA + (kk),             lA + (boA));            \
        async16(gA + (kk) + 16 * CDIM, lA + (boA) + 1024);     \
        async16(gA + (kk) + 32 * CDIM, lA + (boA) + 2048);     \
        async16(gA + (kk) + 48 * CDIM, lA + (boA) + 3072);     \
        async16(gB + (kk),             lB + (boB));            \
        async16(gB + (kk) + 16 * CDIM, lB + (boB) + 1024);     \
    } while (0)

#define COMPUTE(boA, boB)                                                    \
    do {                                                                     \
        i32x8 af0, af1, af2, af3, bg;                                        \
        *(u32x4*)&af0       = *(const u32x4*)&Al[(boA) + rA0 + c0];          \
        *((u32x4*)&af0 + 1) = *(const u32x4*)&Al[(boA) + rA0 + (c0 ^ 16)];   \
        *(u32x4*)&af1       = *(const u32x4*)&Al[(boA) + rA0 + 2048 + c0];   \
        *((u32x4*)&af1 + 1) = *(const u32x4*)&Al[(boA) + rA0 + 2048 + (c0 ^ 16)]; \
        *(u32x4*)&af2       = *(const u32x4*)&Al[(boA) + rA0 + 4096 + c0];   \
        *((u32x4*)&af2 + 1) = *(const u32x4*)&Al[(boA) + rA0 + 4096 + (c0 ^ 16)]; \
        *(u32x4*)&af3       = *(const u32x4*)&Al[(boA) + rA0 + 6144 + c0];   \
        *((u32x4*)&af3 + 1) = *(const u32x4*)&Al[(boA) + rA0 + 6144 + (c0 ^ 16)]; \
        *(u32x4*)&bg        = *(const u32x4*)&Bl[(boB) + rB0 + c0];          \
        *((u32x4*)&bg + 1)  = *(const u32x4*)&Bl[(boB) + rB0 + (c0 ^ 16)];   \
        __builtin_amdgcn_s_setprio(1);                                       \
        acc[0][0] = __builtin_amdgcn_mfma_scale_f32_32x32x64_f8f6f4(         \
            bg, af0, acc[0][0], 0, 0, 0, 0x7F7F7F7F, 0, 0x7F7F7F7F);         \
        acc[0][1] = __builtin_amdgcn_mfma_scale_f32_32x32x64_f8f6f4(         \
            bg, af1, acc[0][1], 0, 0, 0, 0x7F7F7F7F, 0, 0x7F7F7F7F);         \
        acc[0][2] = __builtin_amdgcn_mfma_scale_f32_32x32x64_f8f6f4(         \
            bg, af2, acc[0][2], 0, 0, 0, 0x7F7F7F7F, 0, 0x7F7F7F7F);         \
        acc[0][3] = __builtin_amdgcn_mfma_scale_f32_32x32x64_f8f6f4(         \
            bg, af3, acc[0][3], 0, 0, 0, 0x7F7F7F7F, 0, 0x7F7F7F7F);         \
        *(u32x4*)&bg        = *(const u32x4*)&Bl[(boB) + rB0 + 2048 + c0];   \
        *((u32x4*)&bg + 1)  = *(const u32x4*)&Bl[(boB) + rB0 + 2048 + (c0 ^ 16)]; \
        acc[1][0] = __builtin_amdgcn_mfma_scale_f32_32x32x64_f8f6f4(         \
            bg, af0, acc[1][0], 0, 0, 0, 0x7F7F7F7F, 0, 0x7F7F7F7F);         \
        acc[1][1] = __builtin_amdgcn_mfma_scale_f32_32x32x64_f8f6f4(         \
            bg, af1, acc[1][1], 0, 0, 0, 0x7F7F7F7F, 0, 0x7F7F7F7F);         \
        acc[1][2] = __builtin_amdgcn_mfma_scale_f32_32x32x64_f8f6f4(         \
            bg, af2, acc[1][2], 0, 0, 0, 0x7F7F7F7F, 0, 0x7F7F7F7F);         \
        acc[1][3] = __builtin_amdgcn_mfma_scale_f32_32x32x64_f8f6f4(         \
            bg, af3, acc[1][3], 0, 0, 0, 0x7F7F7F7F, 0, 0x7F7F7F7F);         \
        __builtin_amdgcn_s_setprio(0);                                       \
    } while (0)

#define WAITN(n) asm volatile("s_waitcnt vmcnt(" #n ")" ::: "memory")

    // prologue: stage tiles 0 (buf0) and 1 (buf1); no drain yet.
    STAGE(0, 0, 0);
    STAGE(16384, 8192, 64);

    // steady state: tiles 0..8 computed, tiles 2..10 staged (buf = t%3).
#pragma unroll 1
    for (int r = 0; r < 3; ++r) {
        const int t0 = r * 3;
        WAITN(6);                          // tile t0 landed (t0+1 in flight)
        __builtin_amdgcn_s_barrier();
        STAGE(2 * 16384, 2 * 8192, (t0 + 2) * 64);
        COMPUTE(0, 0);                     // tile t0     (buf 0)
        WAITN(6);                          // tile t0+1 landed
        __builtin_amdgcn_s_barrier();
        STAGE(0, 0, (t0 + 3) * 64);
        COMPUTE(16384, 8192);              // tile t0+1   (buf 1)
        WAITN(6);                          // tile t0+2 landed
        __builtin_amdgcn_s_barrier();
        STAGE(16384, 8192, (t0 + 4) * 64);
        COMPUTE(2 * 16384, 2 * 8192);      // tile t0+2   (buf 2)
    }
    // epilogue of pipeline: computed 0..8, staged 0..10.
    WAITN(6);                              // tile 9 landed (10's in flight)
    __builtin_amdgcn_s_barrier();
    STAGE(2 * 16384, 2 * 8192, 11 * 64);   // tile 11 -> buf 2
    COMPUTE(0, 0);                         // tile 9  (buf 0)
    WAITN(6);                              // tile 10 landed (11's in flight)
    __builtin_amdgcn_s_barrier();
    COMPUTE(16384, 8192);                  // tile 10 (buf 1)
    WAITN(0);                              // tile 11 landed
    __builtin_amdgcn_s_barrier();
    COMPUTE(2 * 16384, 2 * 8192);          // tile 11 (buf 2)

#undef STAGE
#undef COMPUTE
#undef WAITN

    // epilogue: normalize by per-j inv-denom (precomputed, reg-indexed),
    // lane-local argmax over 32 j's per mi, one hi-exchange + atomicMax.
    float bv[4] = {-1e30f, -1e30f, -1e30f, -1e30f};
    int   bj[4] = {0, 0, 0, 0};
#pragma unroll
    for (int nj = 0; nj < 2; ++nj) {
        const int jb = j0 + wj * 64 + nj * 32 + 4 * hi;
        f32x4 iv[4];
#pragma unroll
        for (int q = 0; q < 4; ++q)
            iv[q] = *(const f32x4*)&invdb[jb + 8 * q];
#pragma unroll
        for (int mi = 0; mi < 4; ++mi) {
#pragma unroll
            for (int r = 0; r < 16; ++r) {
                int j = jb + (r & 3) + 8 * (r >> 2);
                float v = acc[nj][mi][r] * iv[r >> 2][r & 3];
                if (v > bv[mi] || (v == bv[mi] && j < bj[mi])) {
                    bv[mi] = v; bj[mi] = j;
                }
            }
        }
    }
#pragma unroll
    for (int mi = 0; mi < 4; ++mi) {
        float ov = __shfl_xor(bv[mi], 32, 64);
        int   oj = __shfl_xor(bj[mi], 32, 64);
        if (ov > bv[mi] || (ov == bv[mi] && oj < bj[mi])) {
            bv[mi] = ov; bj[mi] = oj;
        }
        if (hi == 0) {
            int gi = i0 + wi * 128 + mi * 32 + l31;
            uint32_t u = __float_as_uint(bv[mi]);
            u = (u & 0x80000000u) ? ~u : (u | 0x80000000u);  // orderable f32
            unsigned long long packed =
                ((unsigned long long)u << 32) | (uint32_t)(~(uint32_t)bj[mi]);
            atomicMax(&best[gi], packed);  // ties -> larger ~j -> smaller j
        }
    }
}

// ---- Kernel 3: final loss from stored argmax dot (no gather) ----
// stored v = 128 * dot(a_i, b_j) / denom_b[j]  (fp8 dot, fp32 denom)
__global__ void loss_reduce(const unsigned long long* __restrict__ best,
                            const float* __restrict__ sumsq_a,
                            const float* __restrict__ sumsq_b,
                            float* __restrict__ out) {
    int i = blockIdx.x * 256 + threadIdx.x;
    unsigned long long pk = best[i];
    uint32_t x = (uint32_t)(pk >> 32);
    float v = (x & 0x80000000u) ? __uint_as_float(x & 0x7fffffffu)
                                : __uint_as_float(~x);
    int j = (int)(~(uint32_t)pk);
    float sb = sumsq_b[j];
    float denb = sqrtf(sb + EPSF) + EPSF;
    float dot = v * denb * (1.0f / 128.0f);
    float cs = dot / ((sqrtf(sumsq_a[i]) + EPSF) * (sqrtf(sb) + EPSF));
    float term = 1.0f - cs;
#pragma unroll
    for (int m = 32; m; m >>= 1) term += __shfl_down(term, m, 64);
    __shared__ float red[4];
    int wv = threadIdx.x >> 6, lane = threadIdx.x & 63;
    if (lane == 0) red[wv] = term;
    __syncthreads();
    if (threadIdx.x == 0) {
        float ssum = (red[0] + red[1] + red[2] + red[3]) * (1.0f / HW);
        atomicAdd(out, ssum);
    }
}

extern "C" void kernel_launch(void* const* d_in, const int* in_sizes, int n_in,
                              void* d_out, int out_size, void* d_ws, size_t ws_size,
                              hipStream_t stream) {
    const float* a = (const float*)d_in[0];
    const float* b = (const float*)d_in[1];
    char* ws = (char*)d_ws;

    const size_t T_BYTES = (size_t)HW * CDIM;   // 12.58 MB per fp8 matrix
    uint8_t* at8 = (uint8_t*)ws;
    uint8_t* bn8 = (uint8_t*)(ws + T_BYTES);
    float* sumsq_a = (float*)(ws + 2 * T_BYTES);
    float* sumsq_b = (float*)(ws + 2 * T_BYTES + HW * sizeof(float));
    unsigned long long* best =
        (unsigned long long*)(ws + 2 * T_BYTES + 2 * HW * sizeof(float));
    float* invdb = (float*)(ws + 2 * T_BYTES + 2 * HW * sizeof(float)
                            + HW * sizeof(unsigned long long));

    // zero sumsq_a + sumsq_b + best in one contiguous memset
    hipMemsetAsync(sumsq_a, 0, 2 * HW * sizeof(float) + HW * sizeof(unsigned long long),
                   stream);
    hipMemsetAsync(d_out, 0, out_size * sizeof(float), stream);

    dim3 tg(HW / 64, CDIM / 64, 2);
    transpose_fp8_norm<<<tg, 256, 0, stream>>>(a, b, at8, bn8, sumsq_a, sumsq_b);
    prep_invd<<<HW / 256, 256, 0, stream>>>(sumsq_b, invdb);
    gemm_argmax<<<(HW / 256) * (HW / 128), 256, 0, stream>>>(at8, bn8, invdb, best);
    loss_reduce<<<HW / 256, 256, 0, stream>>>(best, sumsq_a, sumsq_b, (float*)d_out);
}

// Round 6
// 407.196 us; speedup vs baseline: 1.1965x; 1.1965x over previous
//
#include <hip/hip_runtime.h>
#include <stdint.h>

#define HW 16384
#define CDIM 768
#define EPSF 1e-8f

typedef float f32x4  __attribute__((ext_vector_type(4)));
typedef float f32x16 __attribute__((ext_vector_type(16)));
typedef int   i32x8  __attribute__((ext_vector_type(8)));
typedef uint32_t u32x4 __attribute__((ext_vector_type(4)));

__device__ inline void async16(const void* g, void* l) {
    __builtin_amdgcn_global_load_lds(
        (const __attribute__((address_space(1))) uint32_t*)g,
        (__attribute__((address_space(3))) uint32_t*)l, 16, 0, 0);
}

__device__ inline uint32_t pk4_fp8(float v0, float v1, float v2, float v3) {
    uint32_t r = __builtin_amdgcn_cvt_pk_fp8_f32(v0, v1, 0, false);
    r = __builtin_amdgcn_cvt_pk_fp8_f32(v2, v3, r, true);
    return r;   // bytes [v0,v1,v2,v3] little-endian
}

// ---- Kernel 1: fused transpose [C][HW] fp32 -> [HW][C] fp8 + column sum-sq ----
// z=0: a (scale x16), z=1: b (scale x8, RAW; normalization in GEMM epilogue).
__global__ void __launch_bounds__(256)
transpose_fp8_norm(const float* __restrict__ a, const float* __restrict__ b,
                   uint8_t* __restrict__ at8, uint8_t* __restrict__ bn8,
                   float* __restrict__ sumsq_a, float* __restrict__ sumsq_b) {
    const int z = blockIdx.z;
    const float* src = z ? b : a;
    uint8_t* dst = z ? bn8 : at8;
    float* sums = z ? sumsq_b : sumsq_a;
    const float mult = z ? 8.0f : 16.0f;

    __shared__ float tile[64][65];   // [channel][spatial], +1 pad
    const int s0 = blockIdx.x * 64, c0 = blockIdx.y * 64;
    const int tx = threadIdx.x & 63, ty = threadIdx.x >> 6;
#pragma unroll
    for (int p = 0; p < 16; ++p) {
        int cl = p * 4 + ty;
        tile[cl][tx] = src[(size_t)(c0 + cl) * HW + s0 + tx];
    }
    __syncthreads();

    const int chgrp = tx & 15, rowsub = tx >> 4;
    uint32_t* dst32 = (uint32_t*)dst;
#pragma unroll
    for (int p = 0; p < 4; ++p) {
        int sl = p * 16 + ty * 4 + rowsub;
        float v0 = tile[chgrp * 4 + 0][sl];
        float v1 = tile[chgrp * 4 + 1][sl];
        float v2 = tile[chgrp * 4 + 2][sl];
        float v3 = tile[chgrp * 4 + 3][sl];
        float part = v0 * v0 + v1 * v1 + v2 * v2 + v3 * v3;  // raw sum-sq
        dst32[(size_t)(s0 + sl) * (CDIM / 4) + (c0 >> 2) + chgrp] =
            pk4_fp8(v0 * mult, v1 * mult, v2 * mult, v3 * mult);
#pragma unroll
        for (int m = 1; m < 16; m <<= 1) part += __shfl_xor(part, m, 64);
        if (chgrp == 0) atomicAdd(&sums[s0 + sl], part);
    }
}

// ---- Kernel 1b: precompute inverse denominators for b (after atomics) ----
__global__ void prep_invd(const float* __restrict__ sumsq_b,
                          float* __restrict__ invdb) {
    int j = blockIdx.x * 256 + threadIdx.x;
    invdb[j] = 1.0f / (sqrtf(sumsq_b[j] + EPSF) + EPSF);
}

// ---- Kernel 2: MX-scaled fp8 GEMM + normalize + argmax epilogue ----
// Round 14: fix round-5's SPILL, keep its schedule. Evidence r5: WRITE_SIZE
// 33->377 MB + FETCH +147 MB = ~180 B/thread scratch (RA spilled under the
// 6-fold STAGE/COMPUTE macro expansion); all pipes ~22%. The schedule idea
// (3-buffer, counted vmcnt(6), 2 compute phases of load cover for the
// ~1000cy L3-class latency that round 4's 1-phase drain exposed) stands.
// Fix: ROLLED loop -- ONE expansion of STAGE+COMPUTE, runtime buffer
// select (uniform scalars bc/bs cycling 0,1,2 -> SALU + uniform v_adds),
// pragma unroll 1 so the compiler cannot re-expand. Register shape
// returns to round 4's (104 VGPR + acc in AGPRs, no spill).
// Pipeline invariants: at WAITN(6), 12 loads in flight (tiles t+1, t+2)
// -> drains tile t+1 only. WAR: barrier at end of iter t separates last
// read of buf (t-1)%3 from the stage of tile t+2 into that same buf.
// Geometry (round 4): block 256i x 128j, 4 waves, wave tile 128x64,
// 12 b128 reads / 8 MFMA per K-step (ratio 1.5), LDS floor ~150us/CU.
// Same swizzle involution (64B rows, XOR key (row>>1)&3); swapped
// operands -> lane-local argmax. C/D 32x32: col=lane&31,
// row=(reg&3)+8*(reg>>2)+4*(lane>>5).
__global__ void __launch_bounds__(256, 2)
gemm_argmax(const uint8_t* __restrict__ at8, const uint8_t* __restrict__ bn8,
            const float* __restrict__ invdb,
            unsigned long long* __restrict__ best) {
    __shared__ uint8_t Al[3 * 16384];   // [buf][256 rows][64 B]
    __shared__ uint8_t Bl[3 * 8192];    // [buf][128 rows][64 B]

    const int g = blockIdx.x;          // 0..8191
    const int xcd    = g & 7;
    const int s      = g >> 3;         // 0..1023
    const int super  = s >> 5;         // 0..31
    const int within = s & 31;         // 32 blocks / supertile (4i x 8j)
    const int si = super >> 4;         // 0..1
    const int sj = super & 15;         // 0..15
    const int it = xcd * 8 + si * 4 + (within & 3);   // 0..63
    const int jt = sj * 8 + (within >> 2);            // 0..127

    const int i0 = it * 256, j0 = jt * 128;
    const int tid = threadIdx.x;
    const int lane = tid & 63, w = tid >> 6;
    const int wi = w & 1, wj = w >> 1;
    const int l31 = lane & 31, hi = lane >> 5;

    f32x16 acc[2][4] = {};   // [nj][mi]: rows j (regs), cols i (lanes)

    // staging (per 1KB issue: 16 rows x 64B): lane l -> row (l>>2),
    // global chunk (l&3)^((l>>3)&3) [== (row>>1)&3], LDS linear.
    const int srow = lane >> 2;
    const int schunk = ((lane & 3) ^ ((lane >> 3) & 3)) * 16;
    // wave stages 64 rows of A (4 issues), 32 rows of B (2 issues)
    const uint8_t* gAs = at8 + (size_t)(i0 + w * 64 + srow) * CDIM + schunk;
    const uint8_t* gBs = bn8 + (size_t)(j0 + w * 32 + srow) * CDIM + schunk;
    uint8_t* lA = Al + w * 4096;
    uint8_t* lB = Bl + w * 2048;

    // fragment reads: A row = wi*128 + mi*32 + l31; B row = wj*64 + nj*32 + l31
    // lane K-bytes hi*32.. -> logical chunks hi*2, hi*2+1; phys = ^((row>>1)&3)
    const int rA0 = (wi * 128 + l31) * 64;
    const int rB0 = (wj * 64 + l31) * 64;
    const int c0 = ((hi * 2) ^ ((l31 >> 1) & 3)) * 16;   // pair at c0^16

#define STAGE(boA, boB)                                        \
    do {                                                       \
        async16(gAs,             lA + (boA));                  \
        async16(gAs + 16 * CDIM, lA + (boA) + 1024);           \
        async16(gAs + 32 * CDIM, lA + (boA) + 2048);           \
        async16(gAs + 48 * CDIM, lA + (boA) + 3072);           \
        async16(gBs,             lB + (boB));                  \
        async16(gBs + 16 * CDIM, lB + (boB) + 1024);           \
        gAs += 64; gBs += 64;                                  \
    } while (0)

#define COMPUTE(boA, boB)                                                    \
    do {                                                                     \
        i32x8 af0, af1, af2, af3, bg;                                        \
        *(u32x4*)&af0       = *(const u32x4*)&Al[(boA) + rA0 + c0];          \
        *((u32x4*)&af0 + 1) = *(const u32x4*)&Al[(boA) + rA0 + (c0 ^ 16)];   \
        *(u32x4*)&af1       = *(const u32x4*)&Al[(boA) + rA0 + 2048 + c0];   \
        *((u32x4*)&af1 + 1) = *(const u32x4*)&Al[(boA) + rA0 + 2048 + (c0 ^ 16)]; \
        *(u32x4*)&af2       = *(const u32x4*)&Al[(boA) + rA0 + 4096 + c0];   \
        *((u32x4*)&af2 + 1) = *(const u32x4*)&Al[(boA) + rA0 + 4096 + (c0 ^ 16)]; \
        *(u32x4*)&af3       = *(const u32x4*)&Al[(boA) + rA0 + 6144 + c0];   \
        *((u32x4*)&af3 + 1) = *(const u32x4*)&Al[(boA) + rA0 + 6144 + (c0 ^ 16)]; \
        *(u32x4*)&bg        = *(const u32x4*)&Bl[(boB) + rB0 + c0];          \
        *((u32x4*)&bg + 1)  = *(const u32x4*)&Bl[(boB) + rB0 + (c0 ^ 16)];   \
        __builtin_amdgcn_s_setprio(1);                                       \
        acc[0][0] = __builtin_amdgcn_mfma_scale_f32_32x32x64_f8f6f4(         \
            bg, af0, acc[0][0], 0, 0, 0, 0x7F7F7F7F, 0, 0x7F7F7F7F);         \
        acc[0][1] = __builtin_amdgcn_mfma_scale_f32_32x32x64_f8f6f4(         \
            bg, af1, acc[0][1], 0, 0, 0, 0x7F7F7F7F, 0, 0x7F7F7F7F);         \
        acc[0][2] = __builtin_amdgcn_mfma_scale_f32_32x32x64_f8f6f4(         \
            bg, af2, acc[0][2], 0, 0, 0, 0x7F7F7F7F, 0, 0x7F7F7F7F);         \
        acc[0][3] = __builtin_amdgcn_mfma_scale_f32_32x32x64_f8f6f4(         \
            bg, af3, acc[0][3], 0, 0, 0, 0x7F7F7F7F, 0, 0x7F7F7F7F);         \
        *(u32x4*)&bg        = *(const u32x4*)&Bl[(boB) + rB0 + 2048 + c0];   \
        *((u32x4*)&bg + 1)  = *(const u32x4*)&Bl[(boB) + rB0 + 2048 + (c0 ^ 16)]; \
        acc[1][0] = __builtin_amdgcn_mfma_scale_f32_32x32x64_f8f6f4(         \
            bg, af0, acc[1][0], 0, 0, 0, 0x7F7F7F7F, 0, 0x7F7F7F7F);         \
        acc[1][1] = __builtin_amdgcn_mfma_scale_f32_32x32x64_f8f6f4(         \
            bg, af1, acc[1][1], 0, 0, 0, 0x7F7F7F7F, 0, 0x7F7F7F7F);         \
        acc[1][2] = __builtin_amdgcn_mfma_scale_f32_32x32x64_f8f6f4(         \
            bg, af2, acc[1][2], 0, 0, 0, 0x7F7F7F7F, 0, 0x7F7F7F7F);         \
        acc[1][3] = __builtin_amdgcn_mfma_scale_f32_32x32x64_f8f6f4(         \
            bg, af3, acc[1][3], 0, 0, 0, 0x7F7F7F7F, 0, 0x7F7F7F7F);         \
        __builtin_amdgcn_s_setprio(0);                                       \
    } while (0)

#define WAITN(n) asm volatile("s_waitcnt vmcnt(" #n ")" ::: "memory")

    // prologue: stage tiles 0 (buf0), 1 (buf1); wait tile 0 only.
    STAGE(0, 0);
    STAGE(16384, 8192);
    WAITN(6);
    __builtin_amdgcn_s_barrier();

    // rolled steady state: iter t stages tile t+2, computes tile t.
    // bc = t%3 (compute buf), bs = (t+2)%3 (stage buf) -- uniform scalars.
    int bc = 0, bs = 2;
#pragma unroll 1
    for (int t = 0; t < 10; ++t) {
        STAGE(bs * 16384, bs * 8192);
        COMPUTE(bc * 16384, bc * 8192);
        WAITN(6);                          // tile t+1 landed (t+2 in flight)
        __builtin_amdgcn_s_barrier();
        bc = (bc == 2) ? 0 : bc + 1;
        bs = (bs == 2) ? 0 : bs + 1;
    }
    COMPUTE(1 * 16384, 1 * 8192);          // tile 10 (buf 1)
    WAITN(0);                              // tile 11 landed
    __builtin_amdgcn_s_barrier();
    COMPUTE(2 * 16384, 2 * 8192);          // tile 11 (buf 2)

#undef STAGE
#undef COMPUTE
#undef WAITN

    // epilogue: normalize by per-j inv-denom (precomputed, reg-indexed),
    // lane-local argmax over 32 j's per mi, one hi-exchange + atomicMax.
    float bv[4] = {-1e30f, -1e30f, -1e30f, -1e30f};
    int   bj[4] = {0, 0, 0, 0};
#pragma unroll
    for (int nj = 0; nj < 2; ++nj) {
        const int jb = j0 + wj * 64 + nj * 32 + 4 * hi;
        f32x4 iv[4];
#pragma unroll
        for (int q = 0; q < 4; ++q)
            iv[q] = *(const f32x4*)&invdb[jb + 8 * q];
#pragma unroll
        for (int mi = 0; mi < 4; ++mi) {
#pragma unroll
            for (int r = 0; r < 16; ++r) {
                int j = jb + (r & 3) + 8 * (r >> 2);
                float v = acc[nj][mi][r] * iv[r >> 2][r & 3];
                if (v > bv[mi] || (v == bv[mi] && j < bj[mi])) {
                    bv[mi] = v; bj[mi] = j;
                }
            }
        }
    }
#pragma unroll
    for (int mi = 0; mi < 4; ++mi) {
        float ov = __shfl_xor(bv[mi], 32, 64);
        int   oj = __shfl_xor(bj[mi], 32, 64);
        if (ov > bv[mi] || (ov == bv[mi] && oj < bj[mi])) {
            bv[mi] = ov; bj[mi] = oj;
        }
        if (hi == 0) {
            int gi = i0 + wi * 128 + mi * 32 + l31;
            uint32_t u = __float_as_uint(bv[mi]);
            u = (u & 0x80000000u) ? ~u : (u | 0x80000000u);  // orderable f32
            unsigned long long packed =
                ((unsigned long long)u << 32) | (uint32_t)(~(uint32_t)bj[mi]);
            atomicMax(&best[gi], packed);  // ties -> larger ~j -> smaller j
        }
    }
}

// ---- Kernel 3: final loss from stored argmax dot (no gather) ----
// stored v = 128 * dot(a_i, b_j) / denom_b[j]  (fp8 dot, fp32 denom)
__global__ void loss_reduce(const unsigned long long* __restrict__ best,
                            const float* __restrict__ sumsq_a,
                            const float* __restrict__ sumsq_b,
                            float* __restrict__ out) {
    int i = blockIdx.x * 256 + threadIdx.x;
    unsigned long long pk = best[i];
    uint32_t x = (uint32_t)(pk >> 32);
    float v = (x & 0x80000000u) ? __uint_as_float(x & 0x7fffffffu)
                                : __uint_as_float(~x);
    int j = (int)(~(uint32_t)pk);
    float sb = sumsq_b[j];
    float denb = sqrtf(sb + EPSF) + EPSF;
    float dot = v * denb * (1.0f / 128.0f);
    float cs = dot / ((sqrtf(sumsq_a[i]) + EPSF) * (sqrtf(sb) + EPSF));
    float term = 1.0f - cs;
#pragma unroll
    for (int m = 32; m; m >>= 1) term += __shfl_down(term, m, 64);
    __shared__ float red[4];
    int wv = threadIdx.x >> 6, lane = threadIdx.x & 63;
    if (lane == 0) red[wv] = term;
    __syncthreads();
    if (threadIdx.x == 0) {
        float ssum = (red[0] + red[1] + red[2] + red[3]) * (1.0f / HW);
        atomicAdd(out, ssum);
    }
}

extern "C" void kernel_launch(void* const* d_in, const int* in_sizes, int n_in,
                              void* d_out, int out_size, void* d_ws, size_t ws_size,
                              hipStream_t stream) {
    const float* a = (const float*)d_in[0];
    const float* b = (const float*)d_in[1];
    char* ws = (char*)d_ws;

    const size_t T_BYTES = (size_t)HW * CDIM;   // 12.58 MB per fp8 matrix
    uint8_t* at8 = (uint8_t*)ws;
    uint8_t* bn8 = (uint8_t*)(ws + T_BYTES);
    float* sumsq_a = (float*)(ws + 2 * T_BYTES);
    float* sumsq_b = (float*)(ws + 2 * T_BYTES + HW * sizeof(float));
    unsigned long long* best =
        (unsigned long long*)(ws + 2 * T_BYTES + 2 * HW * sizeof(float));
    float* invdb = (float*)(ws + 2 * T_BYTES + 2 * HW * sizeof(float)
                            + HW * sizeof(unsigned long long));

    // zero sumsq_a + sumsq_b + best in one contiguous memset
    hipMemsetAsync(sumsq_a, 0, 2 * HW * sizeof(float) + HW * sizeof(unsigned long long),
                   stream);
    hipMemsetAsync(d_out, 0, out_size * sizeof(float), stream);

    dim3 tg(HW / 64, CDIM / 64, 2);
    transpose_fp8_norm<<<tg, 256, 0, stream>>>(a, b, at8, bn8, sumsq_a, sumsq_b);
    prep_invd<<<HW / 256, 256, 0, stream>>>(sumsq_b, invdb);
    gemm_argmax<<<(HW / 256) * (HW / 128), 256, 0, stream>>>(at8, bn8, invdb, best);
    loss_reduce<<<HW / 256, 256, 0, stream>>>(best, sumsq_a, sumsq_b, (float*)d_out);
}

// Round 7
// 401.285 us; speedup vs baseline: 1.2142x; 1.0147x over previous
//
#include <hip/hip_runtime.h>
#include <stdint.h>

#define HW 16384
#define CDIM 768
#define EPSF 1e-8f

typedef float f32x4  __attribute__((ext_vector_type(4)));
typedef float f32x16 __attribute__((ext_vector_type(16)));
typedef int   i32x8  __attribute__((ext_vector_type(8)));
typedef uint32_t u32x4 __attribute__((ext_vector_type(4)));

__device__ inline void async16(const void* g, void* l) {
    __builtin_amdgcn_global_load_lds(
        (const __attribute__((address_space(1))) uint32_t*)g,
        (__attribute__((address_space(3))) uint32_t*)l, 16, 0, 0);
}

__device__ inline uint32_t pk4_fp8(float v0, float v1, float v2, float v3) {
    uint32_t r = __builtin_amdgcn_cvt_pk_fp8_f32(v0, v1, 0, false);
    r = __builtin_amdgcn_cvt_pk_fp8_f32(v2, v3, r, true);
    return r;   // bytes [v0,v1,v2,v3] little-endian
}

// ---- Kernel 1: fused transpose [C][HW] fp32 -> [HW][C] fp8 + column sum-sq ----
// Round 15: load phase vectorized to float4 (16 B/lane; was scalar 4 B).
// 100 MB of fp32 reads dominate this kernel's ~45us.
__global__ void __launch_bounds__(256)
transpose_fp8_norm(const float* __restrict__ a, const float* __restrict__ b,
                   uint8_t* __restrict__ at8, uint8_t* __restrict__ bn8,
                   float* __restrict__ sumsq_a, float* __restrict__ sumsq_b) {
    const int z = blockIdx.z;
    const float* src = z ? b : a;
    uint8_t* dst = z ? bn8 : at8;
    float* sums = z ? sumsq_b : sumsq_a;
    const float mult = z ? 8.0f : 16.0f;

    __shared__ float tile[64][65];   // [channel][spatial], +1 pad
    const int s0 = blockIdx.x * 64, c0 = blockIdx.y * 64;

    // load: 16 lanes x float4 = 64 spatial per channel row; 16 ch rows/pass
    const int lane16 = threadIdx.x & 15, crow = threadIdx.x >> 4;
#pragma unroll
    for (int p = 0; p < 4; ++p) {
        int cl = p * 16 + crow;
        f32x4 v = *(const f32x4*)&src[(size_t)(c0 + cl) * HW + s0 + lane16 * 4];
        tile[cl][lane16 * 4 + 0] = v[0];
        tile[cl][lane16 * 4 + 1] = v[1];
        tile[cl][lane16 * 4 + 2] = v[2];
        tile[cl][lane16 * 4 + 3] = v[3];
    }
    __syncthreads();

    const int tx = threadIdx.x & 63, ty = threadIdx.x >> 6;
    const int chgrp = tx & 15, rowsub = tx >> 4;
    uint32_t* dst32 = (uint32_t*)dst;
#pragma unroll
    for (int p = 0; p < 4; ++p) {
        int sl = p * 16 + ty * 4 + rowsub;
        float v0 = tile[chgrp * 4 + 0][sl];
        float v1 = tile[chgrp * 4 + 1][sl];
        float v2 = tile[chgrp * 4 + 2][sl];
        float v3 = tile[chgrp * 4 + 3][sl];
        float part = v0 * v0 + v1 * v1 + v2 * v2 + v3 * v3;  // raw sum-sq
        dst32[(size_t)(s0 + sl) * (CDIM / 4) + (c0 >> 2) + chgrp] =
            pk4_fp8(v0 * mult, v1 * mult, v2 * mult, v3 * mult);
#pragma unroll
        for (int m = 1; m < 16; m <<= 1) part += __shfl_xor(part, m, 64);
        if (chgrp == 0) atomicAdd(&sums[s0 + sl], part);
    }
}

// ---- Kernel 1b: precompute inverse denominators for b (after atomics) ----
__global__ void prep_invd(const float* __restrict__ sumsq_b,
                          float* __restrict__ invdb) {
    int j = blockIdx.x * 256 + threadIdx.x;
    invdb[j] = 1.0f / (sqrtf(sumsq_b[j] + EPSF) + EPSF);
}

// ---- Kernel 2: MX-scaled fp8 GEMM + normalize + argmax epilogue ----
// Round 15: 6-round synthesis -- occupancy is the binding constraint
// (44% occ => 280-291us across ALL schedules; 22% occ => 318-387us).
// So: keep round-3's per-wave shape (64x64 wave tile, acc 64 AGPR + 2 af
// + 1 bg ~ 128 regs/wave -> 4 waves/SIMD) and its proven stage-ahead-1
// schedule, but grow the BLOCK to 128i x 256j with 8 waves (2x4):
//  - staged bytes/FLOP -25% ((128+256)/(128*256) vs (128+128)/128^2)
//    -> staging writes 3.15 -> 2.36 GB, conflicts ~ x0.75
//  - per-block prologue/epilogue amortized over 2x the FLOPs
//  - 2 blocks/CU x 8 waves = 50% occupancy (LDS 2 x 48 KB)
// LDS reads/FLOP unchanged (wave tile unchanged). T5 setprio around MFMA
// (4 waves/SIMD = role diversity). Same 64B-row swizzle involution
// (write: chunk (lane&3)^((lane>>3)&3) == ^((row>>1)&3); read: same key).
// Swapped operands -> lane-local argmax. C/D 32x32: col=lane&31,
// row=(reg&3)+8*(reg>>2)+4*(lane>>5).
__global__ void
gemm_argmax(const uint8_t* __restrict__ at8, const uint8_t* __restrict__ bn8,
            const float* __restrict__ invdb,
            unsigned long long* __restrict__ best) {
    __shared__ uint8_t Al[2 * 8192];    // [buf][128 rows][64 B]
    __shared__ uint8_t Bl[2 * 16384];   // [buf][256 rows][64 B]

    const int g = blockIdx.x;          // 0..8191
    const int xcd    = g & 7;
    const int s      = g >> 3;         // 0..1023
    const int super  = s >> 5;         // 0..31 = si(2b) x sj(3b)
    const int within = s & 31;         // 32 blocks / supertile (4i x 8j)
    const int si = super >> 3;         // 0..3
    const int sj = super & 7;          // 0..7
    const int it = xcd * 16 + si * 4 + (within & 3);   // 0..127
    const int jt = sj * 8 + (within >> 2);             // 0..63

    const int i0 = it * 128, j0 = jt * 256;
    const int tid = threadIdx.x;       // 512 threads = 8 waves
    const int lane = tid & 63, w = tid >> 6;
    const int wi = w & 1, wj = w >> 1;   // wave grid 2i x 4j
    const int l31 = lane & 31, hi = lane >> 5;

    f32x16 acc[2][2] = {};   // [nj][mi]: rows j (regs), cols i (lanes)

    // staging (per 1KB issue: 16 rows x 64B): lane l -> row (l>>2),
    // global chunk (l&3)^((l>>3)&3) [== (row>>1)&3], LDS linear.
    // wave w stages A rows [w*16, w*16+16) (1 issue) and
    //               B rows [w*32, w*32+32) (2 issues) -> 3 async16/wave.
    const int srow = lane >> 2;
    const int schunk = ((lane & 3) ^ ((lane >> 3) & 3)) * 16;
    const uint8_t* gAs = at8 + (size_t)(i0 + w * 16 + srow) * CDIM + schunk;
    const uint8_t* gBs = bn8 + (size_t)(j0 + w * 32 + srow) * CDIM + schunk;
    uint8_t* lA = Al + w * 1024;
    uint8_t* lB = Bl + w * 2048;

    // fragment reads: A row = wi*64 + mi*32 + l31; B row = wj*64 + nj*32 + l31
    // lane K-bytes hi*32.. -> logical chunks hi*2, hi*2+1; phys = ^((row>>1)&3)
    const int rA0 = (wi * 64 + l31) * 64;
    const int rB0 = (wj * 64 + l31) * 64;
    const int c0 = ((hi * 2) ^ ((l31 >> 1) & 3)) * 16;   // pair at c0^16

#define STAGE(boA, boB)                                        \
    do {                                                       \
        async16(gAs,             lA + (boA));                  \
        async16(gBs,             lB + (boB));                  \
        async16(gBs + 16 * CDIM, lB + (boB) + 1024);           \
        gAs += 64; gBs += 64;                                  \
    } while (0)

#define COMPUTE(boA, boB)                                                    \
    do {                                                                     \
        i32x8 af0, af1, bg;                                                  \
        *(u32x4*)&af0       = *(const u32x4*)&Al[(boA) + rA0 + c0];          \
        *((u32x4*)&af0 + 1) = *(const u32x4*)&Al[(boA) + rA0 + (c0 ^ 16)];   \
        *(u32x4*)&af1       = *(const u32x4*)&Al[(boA) + rA0 + 2048 + c0];   \
        *((u32x4*)&af1 + 1) = *(const u32x4*)&Al[(boA) + rA0 + 2048 + (c0 ^ 16)]; \
        *(u32x4*)&bg        = *(const u32x4*)&Bl[(boB) + rB0 + c0];          \
        *((u32x4*)&bg + 1)  = *(const u32x4*)&Bl[(boB) + rB0 + (c0 ^ 16)];   \
        __builtin_amdgcn_s_setprio(1);                                       \
        acc[0][0] = __builtin_amdgcn_mfma_scale_f32_32x32x64_f8f6f4(         \
            bg, af0, acc[0][0], 0, 0, 0, 0x7F7F7F7F, 0, 0x7F7F7F7F);         \
        acc[0][1] = __builtin_amdgcn_mfma_scale_f32_32x32x64_f8f6f4(         \
            bg, af1, acc[0][1], 0, 0, 0, 0x7F7F7F7F, 0, 0x7F7F7F7F);         \
        __builtin_amdgcn_s_setprio(0);                                       \
        *(u32x4*)&bg        = *(const u32x4*)&Bl[(boB) + rB0 + 2048 + c0];   \
        *((u32x4*)&bg + 1)  = *(const u32x4*)&Bl[(boB) + rB0 + 2048 + (c0 ^ 16)]; \
        __builtin_amdgcn_s_setprio(1);                                       \
        acc[1][0] = __builtin_amdgcn_mfma_scale_f32_32x32x64_f8f6f4(         \
            bg, af0, acc[1][0], 0, 0, 0, 0x7F7F7F7F, 0, 0x7F7F7F7F);         \
        acc[1][1] = __builtin_amdgcn_mfma_scale_f32_32x32x64_f8f6f4(         \
            bg, af1, acc[1][1], 0, 0, 0, 0x7F7F7F7F, 0, 0x7F7F7F7F);         \
        __builtin_amdgcn_s_setprio(0);                                       \
    } while (0)

#define WAITN(n) asm volatile("s_waitcnt vmcnt(" #n ")" ::: "memory")

    // prologue: stage tile 0, drain, barrier
    STAGE(0, 0);
    WAITN(0);
    __builtin_amdgcn_s_barrier();

    // stage-ahead-1: iter t stages tile t+1 (latency hides under compute)
#pragma unroll 1
    for (int t = 0; t < 11; ++t) {
        const int boA = (t & 1) * 8192, boB = (t & 1) * 16384;
        STAGE(boA ^ 8192, boB ^ 16384);
        COMPUTE(boA, boB);
        WAITN(0);                          // tile t+1 landed (3 loads)
        __builtin_amdgcn_s_barrier();
    }
    COMPUTE(8192, 16384);                  // tile 11 (odd buffer)

#undef STAGE
#undef COMPUTE
#undef WAITN

    // epilogue: normalize by per-j inv-denom (precomputed, reg-indexed),
    // lane-local argmax over 32 j's per mi, one hi-exchange + atomicMax.
    float bv[2] = {-1e30f, -1e30f};
    int   bj[2] = {0, 0};
#pragma unroll
    for (int nj = 0; nj < 2; ++nj) {
        const int jb = j0 + wj * 64 + nj * 32 + 4 * hi;
        f32x4 iv[4];
#pragma unroll
        for (int q = 0; q < 4; ++q)
            iv[q] = *(const f32x4*)&invdb[jb + 8 * q];
#pragma unroll
        for (int mi = 0; mi < 2; ++mi) {
#pragma unroll
            for (int r = 0; r < 16; ++r) {
                int j = jb + (r & 3) + 8 * (r >> 2);
                float v = acc[nj][mi][r] * iv[r >> 2][r & 3];
                if (v > bv[mi] || (v == bv[mi] && j < bj[mi])) {
                    bv[mi] = v; bj[mi] = j;
                }
            }
        }
    }
#pragma unroll
    for (int mi = 0; mi < 2; ++mi) {
        float ov = __shfl_xor(bv[mi], 32, 64);
        int   oj = __shfl_xor(bj[mi], 32, 64);
        if (ov > bv[mi] || (ov == bv[mi] && oj < bj[mi])) {
            bv[mi] = ov; bj[mi] = oj;
        }
        if (hi == 0) {
            int gi = i0 + wi * 64 + mi * 32 + l31;
            uint32_t u = __float_as_uint(bv[mi]);
            u = (u & 0x80000000u) ? ~u : (u | 0x80000000u);  // orderable f32
            unsigned long long packed =
                ((unsigned long long)u << 32) | (uint32_t)(~(uint32_t)bj[mi]);
            atomicMax(&best[gi], packed);  // ties -> larger ~j -> smaller j
        }
    }
}

// ---- Kernel 3: final loss from stored argmax dot (no gather) ----
// stored v = 128 * dot(a_i, b_j) / denom_b[j]  (fp8 dot, fp32 denom)
__global__ void loss_reduce(const unsigned long long* __restrict__ best,
                            const float* __restrict__ sumsq_a,
                            const float* __restrict__ sumsq_b,
                            float* __restrict__ out) {
    int i = blockIdx.x * 256 + threadIdx.x;
    unsigned long long pk = best[i];
    uint32_t x = (uint32_t)(pk >> 32);
    float v = (x & 0x80000000u) ? __uint_as_float(x & 0x7fffffffu)
                                : __uint_as_float(~x);
    int j = (int)(~(uint32_t)pk);
    float sb = sumsq_b[j];
    float denb = sqrtf(sb + EPSF) + EPSF;
    float dot = v * denb * (1.0f / 128.0f);
    float cs = dot / ((sqrtf(sumsq_a[i]) + EPSF) * (sqrtf(sb) + EPSF));
    float term = 1.0f - cs;
#pragma unroll
    for (int m = 32; m; m >>= 1) term += __shfl_down(term, m, 64);
    __shared__ float red[4];
    int wv = threadIdx.x >> 6, lane = threadIdx.x & 63;
    if (lane == 0) red[wv] = term;
    __syncthreads();
    if (threadIdx.x == 0) {
        float ssum = (red[0] + red[1] + red[2] + red[3]) * (1.0f / HW);
        atomicAdd(out, ssum);
    }
}

extern "C" void kernel_launch(void* const* d_in, const int* in_sizes, int n_in,
                              void* d_out, int out_size, void* d_ws, size_t ws_size,
                              hipStream_t stream) {
    const float* a = (const float*)d_in[0];
    const float* b = (const float*)d_in[1];
    char* ws = (char*)d_ws;

    const size_t T_BYTES = (size_t)HW * CDIM;   // 12.58 MB per fp8 matrix
    uint8_t* at8 = (uint8_t*)ws;
    uint8_t* bn8 = (uint8_t*)(ws + T_BYTES);
    float* sumsq_a = (float*)(ws + 2 * T_BYTES);
    float* sumsq_b = (float*)(ws + 2 * T_BYTES + HW * sizeof(float));
    unsigned long long* best =
        (unsigned long long*)(ws + 2 * T_BYTES + 2 * HW * sizeof(float));
    float* invdb = (float*)(ws + 2 * T_BYTES + 2 * HW * sizeof(float)
                            + HW * sizeof(unsigned long long));

    // zero sumsq_a + sumsq_b + best in one contiguous memset
    hipMemsetAsync(sumsq_a, 0, 2 * HW * sizeof(float) + HW * sizeof(unsigned long long),
                   stream);
    hipMemsetAsync(d_out, 0, out_size * sizeof(float), stream);

    dim3 tg(HW / 64, CDIM / 64, 2);
    transpose_fp8_norm<<<tg, 256, 0, stream>>>(a, b, at8, bn8, sumsq_a, sumsq_b);
    prep_invd<<<HW / 256, 256, 0, stream>>>(sumsq_b, invdb);
    gemm_argmax<<<(HW / 128) * (HW / 256), 512, 0, stream>>>(at8, bn8, invdb, best);
    loss_reduce<<<HW / 256, 256, 0, stream>>>(best, sumsq_a, sumsq_b, (float*)d_out);
}